// Round 10
// baseline (522.486 us; speedup 1.0000x reference)
//
#include <hip/hip_runtime.h>
#include <math.h>

#define RNUM 14
#define NNODE 100000
#define ENUM 1600000
#define NKEY (RNUM * NNODE)               // 1,400,000 r-major keys (r*N + dst)
#define NBKT ((NKEY + 8191) / 8192)       // 171 coarse buckets (8192 keys each)
#define NFINE 8192
#define SLOT 10240                        // slots/bucket (mean 9362, +9 sigma)
#define NBLK1 ((ENUM + 8191) / 8192)      // 196 scatter blocks
#define NT16 (NNODE / 16)                 // 6250
#define NTB ((NT16 + 15) / 16)            // 391
#define NWIN (NKEY / 32)                  // 43750 32-bin windows (32 | 100000 -> r-uniform)
#define WINREL (NNODE / 32)               // 3125 windows per relation
#define FRAGREL (RNUM + 1)                // 14 relations + root
#define FRAGTOT (2 * FRAGREL * 4096)

typedef __attribute__((ext_vector_type(8))) short bf16x8;
typedef __attribute__((ext_vector_type(4))) float f32x4;

__device__ inline unsigned short f2bf(float f) {
    unsigned u = __builtin_bit_cast(unsigned, f);
    u += 0x7FFF + ((u >> 16) & 1);
    return (unsigned short)(u >> 16);
}
__device__ inline float bf2f(unsigned short h) {
    unsigned u = ((unsigned)h) << 16;
    return __builtin_bit_cast(float, u);
}
__device__ inline int uload(const int* __restrict__ p) {
    return __builtin_amdgcn_readfirstlane(*p);
}

// ---------------- pass 1: bucket scatter (r-major key) ----------------
__global__ void __launch_bounds__(1024) scatter1_k(const int* __restrict__ src,
        const int* __restrict__ dst, const int* __restrict__ et,
        int* __restrict__ bcur, int2* __restrict__ pay) {
    __shared__ int cnt[192];
    __shared__ int rnk[192];
    __shared__ int base[192];
    int t = threadIdx.x;
    if (t < 192) { cnt[t] = 0; rnk[t] = 0; }
    __syncthreads();
    int e0 = blockIdx.x * 8192;
    int k[8], s[8];
#pragma unroll
    for (int j = 0; j < 8; j++) {
        int e = e0 + j * 1024 + t;
        if (e < ENUM) {
            k[j] = et[e] * NNODE + dst[e];
            s[j] = src[e];
            atomicAdd(&cnt[k[j] >> 13], 1);
        } else k[j] = -1;
    }
    __syncthreads();
    if (t < NBKT && cnt[t] > 0) base[t] = atomicAdd(&bcur[t], cnt[t]);
    __syncthreads();
#pragma unroll
    for (int j = 0; j < 8; j++) {
        if (k[j] < 0) continue;
        int b = k[j] >> 13;
        int rk = atomicAdd(&rnk[b], 1);
        int pos = base[b] + rk;
        if (pos >= SLOT) pos = SLOT - 1;      // statistically unreachable guard
        int2 p; p.x = s[j]; p.y = k[j];
        pay[(size_t)b * SLOT + pos] = p;
    }
}

// ---------------- pass 2: in-bucket fine sort -> offs, ssrc, sdst ----------------
__global__ void __launch_bounds__(1024) bsort_k(const int2* __restrict__ pay,
        const int* __restrict__ bcur, int* __restrict__ offs,
        int* __restrict__ ssrc, int* __restrict__ sdst) {
    __shared__ int cnt[NFINE];
    __shared__ int tsum[1024];
    int bkt = blockIdx.x, t = threadIdx.x;
    int e0 = bkt * SLOT;
    int ecnt = uload(bcur + bkt);
    if (ecnt > SLOT) ecnt = SLOT;
#pragma unroll
    for (int i = t; i < NFINE; i += 1024) cnt[i] = 0;
    __syncthreads();
    for (int e = t; e < ecnt; e += 1024) atomicAdd(&cnt[pay[(size_t)e0 + e].y & 8191], 1);
    __syncthreads();
    int loc[8], s = 0;
#pragma unroll
    for (int j = 0; j < 8; j++) { loc[j] = cnt[t * 8 + j]; s += loc[j]; }
    tsum[t] = s;
    __syncthreads();
    for (int o = 1; o < 1024; o <<= 1) {
        int u = (t >= o) ? tsum[t - o] : 0;
        __syncthreads();
        tsum[t] += u;
        __syncthreads();
    }
    int run = tsum[t] - s;
#pragma unroll
    for (int j = 0; j < 8; j++) {
        int idx = t * 8 + j;
        cnt[idx] = run;                      // becomes the fine-bin cursor
        offs[bkt * NFINE + idx] = e0 + run;  // offs[key] (key = bkt*8192 + fine)
        run += loc[j];
    }
    __syncthreads();
    for (int e = t; e < ecnt; e += 1024) {
        int2 p = pay[(size_t)e0 + e];
        int rk = atomicAdd(&cnt[p.y & 8191], 1);
        int pos = e0 + rk;
        ssrc[pos] = p.x;
        sdst[pos] = p.y - (p.y / NNODE) * NNODE;   // dst = key mod N
    }
}

// ---------------- segment-start flags: one byte per edge ----------------
__global__ void sflag_k(const int* __restrict__ offs, unsigned char* __restrict__ sflagB) {
    int b = blockIdx.x * 256 + threadIdx.x;
    if (b >= NKEY) return;
    int p = offs[b], q = offs[b + 1];
    if (p < q) sflagB[p] = 1;    // spurious bucket-gap flags land in unused slots: harmless
}

// ---------------- prep: weight fragments (incl. root as rel RNUM) + x->bf16 ----------------
__global__ void prep_k(const float* __restrict__ w1, const float* __restrict__ comp2,
                       const float* __restrict__ bases2, const float* __restrict__ root1,
                       const float* __restrict__ root2, const float* __restrict__ x,
                       unsigned short* __restrict__ frag1, unsigned short* __restrict__ frag2,
                       unsigned short* __restrict__ xb) {
    int gid = blockIdx.x * 256 + threadIdx.x;
    if (gid < FRAGTOT) {
        int half = gid >= FRAGREL * 4096;
        int idx = gid - half * (FRAGREL * 4096);
        int j = idx & 7, lane = (idx >> 3) & 63, ot = (idx >> 9) & 3, kh = (idx >> 11) & 1, r = idx >> 12;
        int k = kh * 32 + (lane >> 4) * 8 + j;
        int c = ot * 16 + (lane & 15);
        float v;
        if (!half) {
            if (r < RNUM) {
                int bi = k >> 3, bo = c >> 3;
                v = 0.f;
                if (bi == bo) v = w1[((r * 8 + bi) * 8 + (k & 7)) * 8 + (c & 7)];
            } else v = root1[k * 64 + c];
            frag1[idx] = f2bf(v);
        } else {
            if (r < RNUM) {
                float s = 0.f;
#pragma unroll
                for (int b = 0; b < 8; b++) s += comp2[r * 8 + b] * bases2[(b * 64 + k) * 64 + c];
                v = s;
            } else v = root2[k * 64 + c];
            frag2[idx] = f2bf(v);
        }
    } else {
        int idx = gid - FRAGTOT;
        if (idx < NNODE * 64) xb[idx] = f2bf(x[idx]);
    }
}

// ---------------- root GEMM: xrootb = A @ root (W^T-trick, bf16 out) ----------------
__global__ void __launch_bounds__(256) root_k(const unsigned short* __restrict__ A,
                                              const unsigned short* __restrict__ Froot,
                                              unsigned short* __restrict__ xrootb) {
    int tb = blockIdx.x;
    int wave = threadIdx.x >> 6, lane = threadIdx.x & 63;
    bf16x8 wf[2][4];
#pragma unroll
    for (int kh = 0; kh < 2; kh++)
#pragma unroll
        for (int ot = 0; ot < 4; ot++)
            wf[kh][ot] = *(const bf16x8*)(Froot + ((kh * 4 + ot) * 64 + lane) * 8);
    int node16 = lane & 15;
    int kcol = (lane >> 4) * 8;
    int g = lane >> 4;
    for (int s = 0; s < 4; s++) {
        int nt = tb * 16 + wave * 4 + s;
        if (nt >= NT16) break;
        int nbase = nt * 16;
        const unsigned short* Arow = A + (size_t)(nbase + node16) * 64;
        bf16x8 b0 = *(const bf16x8*)(Arow + kcol);
        bf16x8 b1 = *(const bf16x8*)(Arow + 32 + kcol);
        f32x4 acc[4];
#pragma unroll
        for (int ot = 0; ot < 4; ot++) {
            acc[ot] = (f32x4){0.f, 0.f, 0.f, 0.f};
            acc[ot] = __builtin_amdgcn_mfma_f32_16x16x32_bf16(wf[0][ot], b0, acc[ot], 0, 0, 0);
            acc[ot] = __builtin_amdgcn_mfma_f32_16x16x32_bf16(wf[1][ot], b1, acc[ot], 0, 0, 0);
        }
        unsigned short* Yr = xrootb + (size_t)nbase * 64;
#pragma unroll
        for (int ot = 0; ot < 4; ot++) {
            uint2 pv;
            pv.x = (unsigned)f2bf(acc[ot][0]) | ((unsigned)f2bf(acc[ot][1]) << 16);
            pv.y = (unsigned)f2bf(acc[ot][2]) | ((unsigned)f2bf(acc[ot][3]) << 16);
            *(uint2*)(Yr + (size_t)node16 * 64 + ot * 16 + g * 4) = pv;
        }
    }
}

// ---------------- fused transform+seg-max+scatter-add aggregation ----------------
// wave = 32 consecutive (r,dst) bins (one relation). Gather x rows, MFMA with W_r,
// LDS-transpose, flush-mask segment scan, per-segment 64-lane atomicAdd into outacc.
__global__ void __launch_bounds__(256) fusedagg_k(
    const unsigned short* __restrict__ X, const unsigned short* __restrict__ Frag,
    const int* __restrict__ offs, const int* __restrict__ bcur,
    const int* __restrict__ ssrc, const int* __restrict__ sdst,
    const unsigned char* __restrict__ sflagB, float* __restrict__ outacc) {
    __shared__ float lC[4][16][64];
    int wave = threadIdx.x >> 6, lane = threadIdx.x & 63;
    int win = blockIdx.x * 4 + wave;
    if (win >= NWIN) return;
    int r = __builtin_amdgcn_readfirstlane(win / WINREL);
    int k0 = win * 32;
    const unsigned short* Fr = Frag + (size_t)r * 4096;
    bf16x8 wf[2][4];
#pragma unroll
    for (int kh = 0; kh < 2; kh++)
#pragma unroll
        for (int ot = 0; ot < 4; ot++)
            wf[kh][ot] = *(const bf16x8*)(Fr + ((kh * 4 + ot) * 64 + lane) * 8);
    int e0 = uload(offs + k0);
    int eend;
    if (((k0 + 32) & 8191) == 0) {              // window ends at a bucket boundary
        int bkt = k0 >> 13;
        int ec = uload(bcur + bkt);
        if (ec > SLOT) ec = SLOT;
        eend = bkt * SLOT + ec;
    } else {
        eend = uload(offs + k0 + 32);
    }
    float m = 0.f;
    int curdst = -1;
    for (int cb = e0; cb < eend; cb += 64) {
        int idx = cb + lane;
        int cidx = (idx < eend) ? idx : eend - 1;
        int sv = ssrc[cidx];
        int dv = sdst[cidx];
        int fb = (idx < eend) ? sflagB[cidx] : 0;
        unsigned long long mask = __ballot(fb != 0);
        int n = eend - cb; if (n > 64) n = 64;
        int nsub = (n + 15) >> 4;
        // prologue gather for subtile 0
        int row = __shfl(sv, (lane & 15), 64);
        const unsigned short* xr = X + (size_t)row * 64 + (lane >> 4) * 8;
        bf16x8 a0 = *(const bf16x8*)xr;
        bf16x8 a1 = *(const bf16x8*)(xr + 32);
        for (int t = 0; t < nsub; t++) {
            bf16x8 na0, na1;
            if (t + 1 < nsub) {   // prefetch next subtile while we compute
                int nrow = __shfl(sv, (t + 1) * 16 + (lane & 15), 64);
                const unsigned short* nxr = X + (size_t)nrow * 64 + (lane >> 4) * 8;
                na0 = *(const bf16x8*)nxr;
                na1 = *(const bf16x8*)(nxr + 32);
            }
            f32x4 acc[4];
#pragma unroll
            for (int ot = 0; ot < 4; ot++) {
                acc[ot] = (f32x4){0.f, 0.f, 0.f, 0.f};
                acc[ot] = __builtin_amdgcn_mfma_f32_16x16x32_bf16(a0, wf[0][ot], acc[ot], 0, 0, 0);
                acc[ot] = __builtin_amdgcn_mfma_f32_16x16x32_bf16(a1, wf[1][ot], acc[ot], 0, 0, 0);
            }
            // C -> LDS (wave-private): row = edge-in-subtile, col = feat
#pragma unroll
            for (int ot = 0; ot < 4; ot++)
#pragma unroll
                for (int j = 0; j < 4; j++)
                    lC[wave][(lane >> 4) * 4 + j][ot * 16 + (lane & 15)] = acc[ot][j];
            int lim = n - t * 16; if (lim > 16) lim = 16;
            for (int e = 0; e < lim; e++) {
                int kk = t * 16 + e;
                float v = lC[wave][e][lane];
                if ((mask >> kk) & 1) {
                    if (curdst >= 0) atomicAdd(&outacc[(size_t)curdst * 64 + lane], m);
                    curdst = __builtin_amdgcn_readlane(dv, kk);
                    m = v;
                } else {
                    m = fmaxf(m, v);
                }
            }
            a0 = na0; a1 = na1;
        }
    }
    if (curdst >= 0) atomicAdd(&outacc[(size_t)curdst * 64 + lane], m);
}

// ---------------- finalize ----------------
__global__ void fin1_k(const float* __restrict__ agg1f, const unsigned short* __restrict__ xrootb,
                       const float* __restrict__ bias, unsigned short* __restrict__ x1b) {
    int idx = blockIdx.x * 256 + threadIdx.x;
    if (idx >= NNODE * 64) return;
    float v = agg1f[idx] + bf2f(xrootb[idx]) + bias[idx & 63];
    x1b[idx] = f2bf(fmaxf(v, 0.f));
}

__global__ void fin2_k(float* __restrict__ out, const unsigned short* __restrict__ xrootb,
                       const float* __restrict__ bias) {
    int idx = blockIdx.x * 256 + threadIdx.x;
    if (idx >= NNODE * 64) return;
    out[idx] += bf2f(xrootb[idx]) + bias[idx & 63];
}

extern "C" void kernel_launch(void* const* d_in, const int* in_sizes, int n_in,
                              void* d_out, int out_size, void* d_ws, size_t ws_size,
                              hipStream_t stream) {
    const float* x      = (const float*)d_in[0];
    const int*   ei     = (const int*)d_in[1];
    const int*   et     = (const int*)d_in[2];
    const float* w1     = (const float*)d_in[3];
    const float* root1  = (const float*)d_in[4];
    const float* bias1  = (const float*)d_in[5];
    const float* comp2  = (const float*)d_in[6];
    const float* bases2 = (const float*)d_in[7];
    const float* root2  = (const float*)d_in[8];
    const float* bias2  = (const float*)d_in[9];
    const int* srcv = ei;
    const int* dstv = ei + ENUM;
    float* out = (float*)d_out;

    char* w = (char*)d_ws;
    size_t off = 0;
    auto alloc = [&](size_t bytes) -> void* {
        void* p = w + off;
        off += (bytes + 255) & ~(size_t)255;
        return p;
    };
    int*   offs   = (int*)alloc(((size_t)NBKT * NFINE + 1) * sizeof(int));
    int*   bcur   = (int*)alloc(256 * sizeof(int));
    int2*  pay    = (int2*)alloc((size_t)NBKT * SLOT * sizeof(int2));
    int*   ssrc   = (int*)alloc((size_t)NBKT * SLOT * sizeof(int));
    int*   sdst   = (int*)alloc((size_t)NBKT * SLOT * sizeof(int));
    unsigned char* sflagB = (unsigned char*)alloc((size_t)NBKT * SLOT);
    unsigned short* xb     = (unsigned short*)alloc((size_t)NNODE * 64 * 2); // also x1b
    unsigned short* xrootb = (unsigned short*)alloc((size_t)NNODE * 64 * 2);
    unsigned short* frag1  = (unsigned short*)alloc((size_t)FRAGREL * 4096 * 2);
    unsigned short* frag2  = (unsigned short*)alloc((size_t)FRAGREL * 4096 * 2);
    float* agg1f = (float*)alloc((size_t)NNODE * 64 * sizeof(float));
    if (off > ws_size) return;  // workspace too small — fail visibly

    hipMemsetAsync(bcur, 0, 256 * sizeof(int), stream);
    hipMemsetAsync(sflagB, 0, (size_t)NBKT * SLOT, stream);
    hipMemsetAsync(agg1f, 0, (size_t)NNODE * 64 * sizeof(float), stream);
    hipMemsetAsync(d_out, 0, (size_t)NNODE * 64 * sizeof(float), stream);

    scatter1_k<<<NBLK1, 1024, 0, stream>>>(srcv, dstv, et, bcur, pay);
    bsort_k<<<NBKT, 1024, 0, stream>>>(pay, bcur, offs, ssrc, sdst);
    sflag_k<<<(NKEY + 255) / 256, 256, 0, stream>>>(offs, sflagB);
    prep_k<<<(FRAGTOT + NNODE * 64 + 255) / 256, 256, 0, stream>>>(
        w1, comp2, bases2, root1, root2, x, frag1, frag2, xb);

    int fusedGrid = (NWIN + 3) / 4;
    int finGrid = NNODE * 64 / 256;

    // ---- layer 1 ----
    root_k<<<NTB, 256, 0, stream>>>(xb, frag1 + (size_t)RNUM * 4096, xrootb);
    fusedagg_k<<<fusedGrid, 256, 0, stream>>>(xb, frag1, offs, bcur, ssrc, sdst, sflagB, agg1f);
    fin1_k<<<finGrid, 256, 0, stream>>>(agg1f, xrootb, bias1, xb /* x1b overwrites xb */);

    // ---- layer 2 ----
    root_k<<<NTB, 256, 0, stream>>>(xb, frag2 + (size_t)RNUM * 4096, xrootb);
    fusedagg_k<<<fusedGrid, 256, 0, stream>>>(xb, frag2, offs, bcur, ssrc, sdst, sflagB, out);
    fin2_k<<<finGrid, 256, 0, stream>>>(out, xrootb, bias2);
}

// Round 11
// 483.398 us; speedup vs baseline: 1.0809x; 1.0809x over previous
//
#include <hip/hip_runtime.h>
#include <math.h>

#define RNUM 14
#define NNODE 100000
#define ENUM 1600000
#define NKEY (NNODE * 16)                 // dst-major key: dst*16 + rel
#define NBKT ((NKEY + 8191) / 8192)       // 196 coarse buckets (512 dst each)
#define NFINE 8192
#define SLOT 9216                         // slots/bucket (mean 8163, +11.6 sigma)
#define NBLK1 ((ENUM + 8191) / 8192)      // 196 scatter blocks
#define PREPB 128                         // prep-role blocks appended to scatter launch
#define NT16 (NNODE / 16)                 // 6250
#define NTB ((NT16 + 15) / 16)            // 391
#define FRAGREL (RNUM + 1)                // 14 relations + root
#define FRAGTOT (2 * FRAGREL * 4096)
#define C0 5                              // chunk0 relations (0..4)
#define C1 9                              // chunk1 relations (5..13)
#define AGGGRID (NNODE / 4)

typedef __attribute__((ext_vector_type(8))) short bf16x8;
typedef __attribute__((ext_vector_type(4))) float f32x4;

__device__ inline unsigned short f2bf(float f) {
    unsigned u = __builtin_bit_cast(unsigned, f);
    u += 0x7FFF + ((u >> 16) & 1);
    return (unsigned short)(u >> 16);
}
__device__ inline float bf2f(unsigned short h) {
    unsigned u = ((unsigned)h) << 16;
    return __builtin_bit_cast(float, u);
}
__device__ inline int uload(const int* __restrict__ p) {
    return __builtin_amdgcn_readfirstlane(*p);
}

// ---------------- pass 1: bucket scatter + fused prep ----------------
__global__ void __launch_bounds__(1024) scatter1_k(const int* __restrict__ src,
        const int* __restrict__ dst, const int* __restrict__ et,
        int* __restrict__ bcur, int2* __restrict__ pay,
        const float* __restrict__ w1, const float* __restrict__ comp2,
        const float* __restrict__ bases2, const float* __restrict__ root1,
        const float* __restrict__ root2, const float* __restrict__ x,
        unsigned short* __restrict__ frag1, unsigned short* __restrict__ frag2,
        unsigned short* __restrict__ xb) {
    int t = threadIdx.x;
    if ((int)blockIdx.x >= NBLK1) {
        // ---- prep role: weight fragments + x->bf16, grid-stride ----
        const int TOT = FRAGTOT + NNODE * 64;
        for (int gid = ((int)blockIdx.x - NBLK1) * 1024 + t; gid < TOT; gid += PREPB * 1024) {
            if (gid < FRAGTOT) {
                int half = gid >= FRAGREL * 4096;
                int idx = gid - half * (FRAGREL * 4096);
                int j = idx & 7, lane = (idx >> 3) & 63, ot = (idx >> 9) & 3, kh = (idx >> 11) & 1, r = idx >> 12;
                int k = kh * 32 + (lane >> 4) * 8 + j;
                int c = ot * 16 + (lane & 15);
                float v;
                if (!half) {
                    if (r < RNUM) {
                        int bi = k >> 3, bo = c >> 3;
                        v = 0.f;
                        if (bi == bo) v = w1[((r * 8 + bi) * 8 + (k & 7)) * 8 + (c & 7)];
                    } else v = root1[k * 64 + c];
                    frag1[idx] = f2bf(v);
                } else {
                    if (r < RNUM) {
                        float s = 0.f;
#pragma unroll
                        for (int b = 0; b < 8; b++) s += comp2[r * 8 + b] * bases2[(b * 64 + k) * 64 + c];
                        v = s;
                    } else v = root2[k * 64 + c];
                    frag2[idx] = f2bf(v);
                }
            } else {
                int idx = gid - FRAGTOT;
                xb[idx] = f2bf(x[idx]);
            }
        }
        return;
    }
    // ---- sort-scatter role ----
    __shared__ int cnt[256];
    __shared__ int rnk[256];
    __shared__ int base[256];
    if (t < 256) { cnt[t] = 0; rnk[t] = 0; }
    __syncthreads();
    int e0 = blockIdx.x * 8192;
    int d[8], s[8], r[8];
#pragma unroll
    for (int j = 0; j < 8; j++) {
        int e = e0 + j * 1024 + t;
        if (e < ENUM) {
            d[j] = dst[e]; s[j] = src[e]; r[j] = et[e];
            atomicAdd(&cnt[d[j] >> 9], 1);
        } else d[j] = -1;
    }
    __syncthreads();
    if (t < NBKT && cnt[t] > 0) base[t] = atomicAdd(&bcur[t], cnt[t]);
    __syncthreads();
#pragma unroll
    for (int j = 0; j < 8; j++) {
        if (d[j] < 0) continue;
        int b = d[j] >> 9;
        int rk = atomicAdd(&rnk[b], 1);
        int pos = base[b] + rk;
        if (pos >= SLOT) pos = SLOT - 1;      // statistically unreachable guard
        int2 p; p.x = r[j] * NNODE + s[j]; p.y = (d[j] & 511) * 16 + r[j];
        pay[(size_t)b * SLOT + pos] = p;
    }
}

// ---------------- pass 2: in-bucket fine sort + offs + ssrc ----------------
__global__ void __launch_bounds__(1024) bsort_k(const int2* __restrict__ pay,
        const int* __restrict__ bcur, int* __restrict__ offs, int* __restrict__ ssrc) {
    __shared__ int cnt[NFINE];
    __shared__ int tsum[1024];
    int bkt = blockIdx.x, t = threadIdx.x;
    int e0 = bkt * SLOT;
    int ecnt = uload(bcur + bkt);
    if (ecnt > SLOT) ecnt = SLOT;
#pragma unroll
    for (int i = t; i < NFINE; i += 1024) cnt[i] = 0;
    __syncthreads();
    for (int e = t; e < ecnt; e += 1024) atomicAdd(&cnt[pay[(size_t)e0 + e].y], 1);
    __syncthreads();
    int loc[8], s = 0;
#pragma unroll
    for (int j = 0; j < 8; j++) { loc[j] = cnt[t * 8 + j]; s += loc[j]; }
    tsum[t] = s;
    __syncthreads();
    for (int o = 1; o < 1024; o <<= 1) {
        int u = (t >= o) ? tsum[t - o] : 0;
        __syncthreads();
        tsum[t] += u;
        __syncthreads();
    }
    int run = tsum[t] - s;
#pragma unroll
    for (int j = 0; j < 8; j++) {
        int idx = t * 8 + j;
        cnt[idx] = run;                      // becomes the fine-bin cursor
        offs[bkt * NFINE + idx] = e0 + run;  // absolute slotted positions
        run += loc[j];
    }
    __syncthreads();
    for (int e = t; e < ecnt; e += 1024) {
        int2 p = pay[(size_t)e0 + e];
        int rk = atomicAdd(&cnt[p.y], 1);
        ssrc[e0 + rk] = p.x;                 // p.x = r*NNODE + src
    }
}

// ---------------- duo kernel: gemm-role blocks + agg-role blocks ----------------
// gemm: H[r][n][:] = xb[n][:] @ W[r] (C = W^T X^T, LDS transpose store); ri==grels & groot -> root.
// agg: flat flush-mask segment scan over relation chunk [ar0, ar0+ARC), H rows indexed by ssrc directly.
// aflags: 1=first chunk (store partial), 2=last chunk (finalize), 4=relu+bf16 out (layer 1)
template <int ARC>
__global__ void __launch_bounds__(256) duo_k(
    int ngemmblk, int gr0, int grels, int groot,
    const unsigned short* __restrict__ xb, const unsigned short* __restrict__ frag,
    unsigned short* __restrict__ H, unsigned short* __restrict__ xrootb,
    const int* __restrict__ offs, const int* __restrict__ ssrc,
    int ar0, const float* __restrict__ bias, float* __restrict__ aggbuf,
    unsigned short* __restrict__ x1b, float* __restrict__ outf, int aflags) {
    __shared__ unsigned short tl[4][16][72];
    int wave = threadIdx.x >> 6, lane = threadIdx.x & 63;
    if ((int)blockIdx.x < ngemmblk) {
        int tb = blockIdx.x % NTB;
        int ri = blockIdx.x / NTB;
        bool isroot = groot && (ri == grels);
        int r = gr0 + ri;
        const unsigned short* Fr = frag + (size_t)(isroot ? RNUM : r) * 4096;
        bf16x8 wf[2][4];
#pragma unroll
        for (int kh = 0; kh < 2; kh++)
#pragma unroll
            for (int ot = 0; ot < 4; ot++)
                wf[kh][ot] = *(const bf16x8*)(Fr + ((kh * 4 + ot) * 64 + lane) * 8);
        int node16 = lane & 15;
        int kcol = (lane >> 4) * 8;
        int g = lane >> 4;
        unsigned short* Ybase = isroot ? xrootb : H + (size_t)r * NNODE * 64;
        for (int s = 0; s < 4; s++) {
            int nt = tb * 16 + wave * 4 + s;
            if (nt >= NT16) break;
            int nbase = nt * 16;
            const unsigned short* Arow = xb + (size_t)(nbase + node16) * 64;
            bf16x8 b0 = *(const bf16x8*)(Arow + kcol);
            bf16x8 b1 = *(const bf16x8*)(Arow + 32 + kcol);
            f32x4 acc[4];
#pragma unroll
            for (int ot = 0; ot < 4; ot++) {
                acc[ot] = (f32x4){0.f, 0.f, 0.f, 0.f};
                acc[ot] = __builtin_amdgcn_mfma_f32_16x16x32_bf16(wf[0][ot], b0, acc[ot], 0, 0, 0);
                acc[ot] = __builtin_amdgcn_mfma_f32_16x16x32_bf16(wf[1][ot], b1, acc[ot], 0, 0, 0);
            }
#pragma unroll
            for (int ot = 0; ot < 4; ot++) {
                uint2 pv;
                pv.x = (unsigned)f2bf(acc[ot][0]) | ((unsigned)f2bf(acc[ot][1]) << 16);
                pv.y = (unsigned)f2bf(acc[ot][2]) | ((unsigned)f2bf(acc[ot][3]) << 16);
                *(uint2*)&tl[wave][node16][ot * 16 + g * 4] = pv;
            }
            unsigned short* Yr = Ybase + (size_t)nbase * 64;
#pragma unroll
            for (int q = 0; q < 2; q++) {
                int nd = q * 8 + (lane >> 3);
                int ch = (lane & 7) * 8;
                uint4 v = *(uint4*)&tl[wave][nd][ch];
                *(uint4*)(Yr + (size_t)nd * 64 + ch) = v;
            }
        }
        return;
    }
    if constexpr (ARC > 0) {
        int b = blockIdx.x - ngemmblk;
        int d = __builtin_amdgcn_readfirstlane(b * 4 + wave);
        if (d >= NNODE) return;
        float msum = 0.f;
        const int base = d * 16 + ar0;
        int bnd[ARC + 1];
#pragma unroll
        for (int j = 0; j <= ARC; j++) bnd[j] = offs[base + j];
        int e0   = __builtin_amdgcn_readfirstlane(bnd[0]);
        int eend = __builtin_amdgcn_readfirstlane(bnd[ARC]);
        float m = -INFINITY;
        for (int cb = e0; cb < eend; cb += 64) {
            int idx = cb + lane;
            int cidx = (idx < eend) ? idx : eend - 1;
            int sv = ssrc[cidx];
            unsigned long long mask = 0;
#pragma unroll
            for (int j = 1; j < ARC; j++) {
                int kk_ = bnd[j] - cb;
                if (kk_ >= 0 && kk_ < 64 && bnd[j] > e0) mask |= 1ull << kk_;
            }
            int n = eend - cb; if (n > 64) n = 64;
            for (int k0 = 0; k0 < n; k0 += 16) {
                float h[16];
#pragma unroll
                for (int u = 0; u < 16; u++) {
                    int kk = k0 + u;
                    int kc = (kk < n) ? kk : n - 1;   // tail dups -> merged fetch
                    int s = __builtin_amdgcn_readlane(sv, kc);
                    h[u] = bf2f(H[(size_t)s * 64 + lane]);
                }
#pragma unroll
                for (int u = 0; u < 16; u++) {
                    int kk = k0 + u;
                    if (kk >= n) break;
                    bool fl = (mask >> kk) & 1;
                    msum += fl ? m : 0.f;
                    m = fl ? h[u] : fmaxf(m, h[u]);
                }
            }
        }
        if (eend > e0) msum += m;
        size_t o = (size_t)d * 64 + lane;
        if (!(aflags & 1)) msum += aggbuf[o];
        if (!(aflags & 2)) { aggbuf[o] = msum; return; }
        float v = msum + bf2f(xrootb[o]) + bias[lane];
        if (aflags & 4) x1b[o] = f2bf(fmaxf(v, 0.f));
        else outf[o] = v;
    }
}

extern "C" void kernel_launch(void* const* d_in, const int* in_sizes, int n_in,
                              void* d_out, int out_size, void* d_ws, size_t ws_size,
                              hipStream_t stream) {
    const float* x      = (const float*)d_in[0];
    const int*   ei     = (const int*)d_in[1];
    const int*   et     = (const int*)d_in[2];
    const float* w1     = (const float*)d_in[3];
    const float* root1  = (const float*)d_in[4];
    const float* bias1  = (const float*)d_in[5];
    const float* comp2  = (const float*)d_in[6];
    const float* bases2 = (const float*)d_in[7];
    const float* root2  = (const float*)d_in[8];
    const float* bias2  = (const float*)d_in[9];
    const int* srcv = ei;
    const int* dstv = ei + ENUM;
    float* out = (float*)d_out;

    char* w = (char*)d_ws;
    size_t off = 0;
    auto alloc = [&](size_t bytes) -> void* {
        void* p = w + off;
        off += (bytes + 255) & ~(size_t)255;
        return p;
    };
    int*   offs = (int*)alloc(((size_t)NBKT * NFINE + 1) * sizeof(int));
    int*   bcur = (int*)alloc(256 * sizeof(int));
    int2*  pay  = (int2*)alloc((size_t)NBKT * SLOT * sizeof(int2));
    int*   ssrc = (int*)alloc((size_t)NBKT * SLOT * sizeof(int));
    unsigned short* xb     = (unsigned short*)alloc((size_t)NNODE * 64 * 2); // also x1b
    unsigned short* xrootb = (unsigned short*)alloc((size_t)NNODE * 64 * 2);
    unsigned short* frag1  = (unsigned short*)alloc((size_t)FRAGREL * 4096 * 2);
    unsigned short* frag2  = (unsigned short*)alloc((size_t)FRAGREL * 4096 * 2);
    unsigned short* H      = (unsigned short*)alloc((size_t)RNUM * NNODE * 64 * 2);
    if (off > ws_size) return;  // workspace too small — fail visibly

    float* aggbuf = (float*)d_out;   // partial sums live in d_out (overwritten before read)

    hipMemsetAsync(bcur, 0, 256 * sizeof(int), stream);

    scatter1_k<<<NBLK1 + PREPB, 1024, 0, stream>>>(srcv, dstv, et, bcur, pay,
        w1, comp2, bases2, root1, root2, x, frag1, frag2, xb);
    bsort_k<<<NBKT, 1024, 0, stream>>>(pay, bcur, offs, ssrc);

    for (int layer = 0; layer < 2; layer++) {
        const unsigned short* frag = layer ? frag2 : frag1;
        const float* bias = layer ? bias2 : bias1;
        int lastflags = 2 | (layer == 0 ? 4 : 0);
        // step a: gemm chunk0 (rel 0..C0-1) + root
        duo_k<0><<<(C0 + 1) * NTB, 256, 0, stream>>>(
            (C0 + 1) * NTB, 0, C0, 1, xb, frag, H, xrootb,
            offs, ssrc, 0, bias, aggbuf, xb, out, 0);
        // step b: gemm chunk1 (rel C0..13)  ||  agg chunk0 -> aggbuf
        duo_k<C0><<<C1 * NTB + AGGGRID, 256, 0, stream>>>(
            C1 * NTB, C0, C1, 0, xb, frag, H, xrootb,
            offs, ssrc, 0, bias, aggbuf, xb, out, 1);
        // step c: agg chunk1 + finalize (root + bias [+ relu])
        duo_k<C1><<<AGGGRID, 256, 0, stream>>>(
            0, 0, 0, 0, xb, frag, H, xrootb,
            offs, ssrc, C0, bias, aggbuf, xb, out, lastflags);
    }
}

// Round 12
// 376.234 us; speedup vs baseline: 1.3887x; 1.2848x over previous
//
#include <hip/hip_runtime.h>
#include <math.h>

#define RNUM 14
#define NNODE 100000
#define ENUM 1600000
#define NKEY (NNODE * 16)                 // dst-major key: dst*16 + rel
#define NBKT ((NKEY + 8191) / 8192)       // 196 coarse buckets (512 dst each)
#define NFINE 8192
#define SLOT 9216                         // slots/bucket (mean 8163, +11.6 sigma)
#define NBLK1 ((ENUM + 8191) / 8192)      // 196 scatter blocks
#define PREPB 128                         // prep-role blocks appended to scatter launch
#define NT16 (NNODE / 16)                 // 6250
#define NTB ((NT16 + 15) / 16)            // 391
#define FRAGREL (RNUM + 1)                // 14 relations + root
#define FRAGTOT (2 * FRAGREL * 4096)

typedef __attribute__((ext_vector_type(8))) short bf16x8;
typedef __attribute__((ext_vector_type(4))) float f32x4;

__device__ inline unsigned short f2bf(float f) {
    unsigned u = __builtin_bit_cast(unsigned, f);
    u += 0x7FFF + ((u >> 16) & 1);
    return (unsigned short)(u >> 16);
}
__device__ inline float bf2f(unsigned short h) {
    unsigned u = ((unsigned)h) << 16;
    return __builtin_bit_cast(float, u);
}
__device__ inline int uload(const int* __restrict__ p) {
    return __builtin_amdgcn_readfirstlane(*p);
}

// ---------------- pass 1: bucket scatter + fused prep ----------------
__global__ void __launch_bounds__(1024) scatter1_k(const int* __restrict__ src,
        const int* __restrict__ dst, const int* __restrict__ et,
        int* __restrict__ bcur, int2* __restrict__ pay,
        const float* __restrict__ w1, const float* __restrict__ comp2,
        const float* __restrict__ bases2, const float* __restrict__ root1,
        const float* __restrict__ root2, const float* __restrict__ x,
        unsigned short* __restrict__ frag1, unsigned short* __restrict__ frag2,
        unsigned short* __restrict__ xb) {
    int t = threadIdx.x;
    if ((int)blockIdx.x >= NBLK1) {
        // ---- prep role: weight fragments + x->bf16, grid-stride ----
        const int TOT = FRAGTOT + NNODE * 64;
        for (int gid = ((int)blockIdx.x - NBLK1) * 1024 + t; gid < TOT; gid += PREPB * 1024) {
            if (gid < FRAGTOT) {
                int half = gid >= FRAGREL * 4096;
                int idx = gid - half * (FRAGREL * 4096);
                int j = idx & 7, lane = (idx >> 3) & 63, ot = (idx >> 9) & 3, kh = (idx >> 11) & 1, r = idx >> 12;
                int k = kh * 32 + (lane >> 4) * 8 + j;
                int c = ot * 16 + (lane & 15);
                float v;
                if (!half) {
                    if (r < RNUM) {
                        int bi = k >> 3, bo = c >> 3;
                        v = 0.f;
                        if (bi == bo) v = w1[((r * 8 + bi) * 8 + (k & 7)) * 8 + (c & 7)];
                    } else v = root1[k * 64 + c];
                    frag1[idx] = f2bf(v);
                } else {
                    if (r < RNUM) {
                        float s = 0.f;
#pragma unroll
                        for (int b = 0; b < 8; b++) s += comp2[r * 8 + b] * bases2[(b * 64 + k) * 64 + c];
                        v = s;
                    } else v = root2[k * 64 + c];
                    frag2[idx] = f2bf(v);
                }
            } else {
                int idx = gid - FRAGTOT;
                xb[idx] = f2bf(x[idx]);
            }
        }
        return;
    }
    // ---- sort-scatter role ----
    __shared__ int cnt[256];
    __shared__ int rnk[256];
    __shared__ int base[256];
    if (t < 256) { cnt[t] = 0; rnk[t] = 0; }
    __syncthreads();
    int e0 = blockIdx.x * 8192;
    int d[8], s[8], r[8];
#pragma unroll
    for (int j = 0; j < 8; j++) {
        int e = e0 + j * 1024 + t;
        if (e < ENUM) {
            d[j] = dst[e]; s[j] = src[e]; r[j] = et[e];
            atomicAdd(&cnt[d[j] >> 9], 1);
        } else d[j] = -1;
    }
    __syncthreads();
    if (t < NBKT && cnt[t] > 0) base[t] = atomicAdd(&bcur[t], cnt[t]);
    __syncthreads();
#pragma unroll
    for (int j = 0; j < 8; j++) {
        if (d[j] < 0) continue;
        int b = d[j] >> 9;
        int rk = atomicAdd(&rnk[b], 1);
        int pos = base[b] + rk;
        if (pos >= SLOT) pos = SLOT - 1;      // statistically unreachable guard
        int2 p; p.x = r[j] * NNODE + s[j]; p.y = (d[j] & 511) * 16 + r[j];
        pay[(size_t)b * SLOT + pos] = p;
    }
}

// ---------------- pass 2: in-bucket fine sort + offs + ssrc ----------------
__global__ void __launch_bounds__(1024) bsort_k(const int2* __restrict__ pay,
        const int* __restrict__ bcur, int* __restrict__ offs, int* __restrict__ ssrc) {
    __shared__ int cnt[NFINE];
    __shared__ int tsum[1024];
    int bkt = blockIdx.x, t = threadIdx.x;
    int e0 = bkt * SLOT;
    int ecnt = uload(bcur + bkt);
    if (ecnt > SLOT) ecnt = SLOT;
#pragma unroll
    for (int i = t; i < NFINE; i += 1024) cnt[i] = 0;
    __syncthreads();
    for (int e = t; e < ecnt; e += 1024) atomicAdd(&cnt[pay[(size_t)e0 + e].y], 1);
    __syncthreads();
    int loc[8], s = 0;
#pragma unroll
    for (int j = 0; j < 8; j++) { loc[j] = cnt[t * 8 + j]; s += loc[j]; }
    tsum[t] = s;
    __syncthreads();
    for (int o = 1; o < 1024; o <<= 1) {
        int u = (t >= o) ? tsum[t - o] : 0;
        __syncthreads();
        tsum[t] += u;
        __syncthreads();
    }
    int run = tsum[t] - s;
#pragma unroll
    for (int j = 0; j < 8; j++) {
        int idx = t * 8 + j;
        cnt[idx] = run;                      // becomes the fine-bin cursor
        offs[bkt * NFINE + idx] = e0 + run;  // absolute slotted positions
        run += loc[j];
    }
    __syncthreads();
    for (int e = t; e < ecnt; e += 1024) {
        int2 p = pay[(size_t)e0 + e];
        int rk = atomicAdd(&cnt[p.y], 1);
        ssrc[e0 + rk] = p.x;                 // p.x = r*NNODE + src
    }
}

// ---------------- GEMM: H[r][n][:] = xb[n][:] @ W[r]  (C = W^T X^T, LDS-transpose store) ----------------
// blocks with r < nrel write the bf16 H slab; r == nrel writes the root product.
__global__ void __launch_bounds__(256) gemm_k(const unsigned short* __restrict__ A,
                                              const unsigned short* __restrict__ F,
                                              const unsigned short* __restrict__ Froot,
                                              unsigned short* __restrict__ H,
                                              unsigned short* __restrict__ xrootb,
                                              int nrel) {
    __shared__ unsigned short tl[4][16][72];   // 72-short stride: 16B-aligned rows, bank-spread
    int tb = blockIdx.x % NTB;
    int r  = blockIdx.x / NTB;
    bool isroot = (r == nrel);
    const unsigned short* Fr = isroot ? Froot : F + (size_t)r * 4096;
    int wave = threadIdx.x >> 6, lane = threadIdx.x & 63;
    bf16x8 wf[2][4];
#pragma unroll
    for (int kh = 0; kh < 2; kh++)
#pragma unroll
        for (int ot = 0; ot < 4; ot++)
            wf[kh][ot] = *(const bf16x8*)(Fr + ((kh * 4 + ot) * 64 + lane) * 8);
    int node16 = lane & 15;
    int kcol = (lane >> 4) * 8;
    int g = lane >> 4;
    unsigned short* Ybase = isroot ? xrootb : H + (size_t)r * NNODE * 64;
    for (int s = 0; s < 4; s++) {
        int nt = tb * 16 + wave * 4 + s;
        if (nt >= NT16) break;
        int nbase = nt * 16;
        const unsigned short* Arow = A + (size_t)(nbase + node16) * 64;
        bf16x8 b0 = *(const bf16x8*)(Arow + kcol);
        bf16x8 b1 = *(const bf16x8*)(Arow + 32 + kcol);
        f32x4 acc[4];
#pragma unroll
        for (int ot = 0; ot < 4; ot++) {
            acc[ot] = (f32x4){0.f, 0.f, 0.f, 0.f};
            acc[ot] = __builtin_amdgcn_mfma_f32_16x16x32_bf16(wf[0][ot], b0, acc[ot], 0, 0, 0);
            acc[ot] = __builtin_amdgcn_mfma_f32_16x16x32_bf16(wf[1][ot], b1, acc[ot], 0, 0, 0);
        }
#pragma unroll
        for (int ot = 0; ot < 4; ot++) {
            uint2 pv;
            pv.x = (unsigned)f2bf(acc[ot][0]) | ((unsigned)f2bf(acc[ot][1]) << 16);
            pv.y = (unsigned)f2bf(acc[ot][2]) | ((unsigned)f2bf(acc[ot][3]) << 16);
            *(uint2*)&tl[wave][node16][ot * 16 + g * 4] = pv;
        }
        unsigned short* Yr = Ybase + (size_t)nbase * 64;
#pragma unroll
        for (int q = 0; q < 2; q++) {
            int nd = q * 8 + (lane >> 3);
            int ch = (lane & 7) * 8;
            uint4 v = *(uint4*)&tl[wave][nd][ch];
            *(uint4*)(Yr + (size_t)nd * 64 + ch) = v;
        }
    }
}

// ---------------- aggregation: flat flush-mask edge loop, one wave per node ----------------
// flags: 1=first chunk, 2=last chunk, 4=layer1 (relu + bf16 out to x1b)
template <int RC>
__global__ void __launch_bounds__(256) agg_k(
    const unsigned short* __restrict__ H, const int* __restrict__ offs,
    const int* __restrict__ ssrc, const unsigned short* __restrict__ xrootb,
    const float* __restrict__ bias, float* __restrict__ aggbuf,
    unsigned short* __restrict__ x1b, float* __restrict__ outf,
    int r0, int r0N, int rcnt, int flags) {
    int wv = threadIdx.x >> 6, lane = threadIdx.x & 63;
    int d = __builtin_amdgcn_readfirstlane(blockIdx.x * 4 + wv);
    if (d >= NNODE) return;
    float msum = 0.f;

    if constexpr (RC == RNUM) {
        const int base = d * 16;                 // r0 == 0, 64B-aligned
        int4 q0 = *(const int4*)(offs + base);
        int4 q1 = *(const int4*)(offs + base + 4);
        int4 q2 = *(const int4*)(offs + base + 8);
        int4 q3 = *(const int4*)(offs + base + 12);
        int bnd[15] = {q0.x, q0.y, q0.z, q0.w, q1.x, q1.y, q1.z, q1.w,
                       q2.x, q2.y, q2.z, q2.w, q3.x, q3.y, q3.z};
        int e0   = __builtin_amdgcn_readfirstlane(bnd[0]);
        int eend = __builtin_amdgcn_readfirstlane(bnd[14]);
        float m = -INFINITY;
        for (int cb = e0; cb < eend; cb += 64) {
            int idx = cb + lane;
            int cidx = (idx < eend) ? idx : eend - 1;
            int sv = ssrc[cidx];
            unsigned long long mask = 0;
#pragma unroll
            for (int j = 1; j < 14; j++) {
                int kk_ = bnd[j] - cb;
                if (kk_ >= 0 && kk_ < 64 && bnd[j] > e0) mask |= 1ull << kk_;
            }
            int n = eend - cb; if (n > 64) n = 64;
            for (int k0 = 0; k0 < n; k0 += 16) {
                float h[16];
#pragma unroll
                for (int u = 0; u < 16; u++) {
                    int kk = k0 + u;
                    int kc = (kk < n) ? kk : n - 1;   // tail dups -> merged fetch
                    int s = __builtin_amdgcn_readlane(sv, kc);
                    h[u] = bf2f(H[(size_t)s * 64 + lane]);
                }
#pragma unroll
                for (int u = 0; u < 16; u++) {
                    int kk = k0 + u;
                    if (kk >= n) break;
                    bool fl = (mask >> kk) & 1;
                    msum += fl ? m : 0.f;
                    m = fl ? h[u] : fmaxf(m, h[u]);
                }
            }
        }
        if (eend > e0) msum += m;
    } else {
        const int base = d * 16 + r0;
        for (int j = 0; j < rcnt; j++) {
            int e = uload(offs + base + j);
            int ee = uload(offs + base + j + 1);
            if (e >= ee) continue;
            float m = -INFINITY;
            for (; e < ee; e++) {
                int s = uload(ssrc + e);
                m = fmaxf(m, bf2f(H[(size_t)(s - r0N) * 64 + lane]));
            }
            msum += m;
        }
    }

    size_t o = (size_t)d * 64 + lane;
    if (!(flags & 1)) msum += aggbuf[o];
    if (!(flags & 2)) { aggbuf[o] = msum; return; }
    float v = msum + bf2f(xrootb[o]) + bias[lane];
    if (flags & 4) x1b[o] = f2bf(fmaxf(v, 0.f));
    else outf[o] = v;
}

extern "C" void kernel_launch(void* const* d_in, const int* in_sizes, int n_in,
                              void* d_out, int out_size, void* d_ws, size_t ws_size,
                              hipStream_t stream) {
    const float* x      = (const float*)d_in[0];
    const int*   ei     = (const int*)d_in[1];
    const int*   et     = (const int*)d_in[2];
    const float* w1     = (const float*)d_in[3];
    const float* root1  = (const float*)d_in[4];
    const float* bias1  = (const float*)d_in[5];
    const float* comp2  = (const float*)d_in[6];
    const float* bases2 = (const float*)d_in[7];
    const float* root2  = (const float*)d_in[8];
    const float* bias2  = (const float*)d_in[9];
    const int* srcv = ei;
    const int* dstv = ei + ENUM;
    float* out = (float*)d_out;

    char* w = (char*)d_ws;
    size_t off = 0;
    auto alloc = [&](size_t bytes) -> void* {
        void* p = w + off;
        off += (bytes + 255) & ~(size_t)255;
        return p;
    };
    int*   offs = (int*)alloc(((size_t)NBKT * NFINE + 1) * sizeof(int));
    int*   bcur = (int*)alloc(256 * sizeof(int));
    int2*  pay  = (int2*)alloc((size_t)NBKT * SLOT * sizeof(int2));
    int*   ssrc = (int*)alloc((size_t)NBKT * SLOT * sizeof(int));
    unsigned short* xb     = (unsigned short*)alloc((size_t)NNODE * 64 * 2); // also x1b
    unsigned short* xrootb = (unsigned short*)alloc((size_t)NNODE * 64 * 2);
    unsigned short* frag1  = (unsigned short*)alloc((size_t)FRAGREL * 4096 * 2);
    unsigned short* frag2  = (unsigned short*)alloc((size_t)FRAGREL * 4096 * 2);
    size_t fixed = off;
    if (fixed > ws_size) return;  // fail visibly
    size_t slab = ((size_t)NNODE * 64 * 2 + 255) & ~(size_t)255;   // bf16 rows
    size_t avail = ws_size - fixed;
    int r_per;
    float* aggbuf;
    unsigned short* H;
    if (avail >= (size_t)RNUM * slab) {
        r_per = RNUM;                                      // single chunk, no aggbuf
        H = (unsigned short*)alloc((size_t)RNUM * slab);
        aggbuf = (float*)H;                                // never accessed
    } else {
        aggbuf = (float*)alloc((size_t)NNODE * 64 * 4);
        if (off > ws_size) return;
        avail = ws_size - off;
        r_per = (int)(avail / slab);
        if (r_per < 1) return;
        if (r_per > RNUM) r_per = RNUM;
        H = (unsigned short*)alloc((size_t)r_per * slab);
    }

    hipMemsetAsync(bcur, 0, 256 * sizeof(int), stream);

    scatter1_k<<<NBLK1 + PREPB, 1024, 0, stream>>>(srcv, dstv, et, bcur, pay,
        w1, comp2, bases2, root1, root2, x, frag1, frag2, xb);
    bsort_k<<<NBKT, 1024, 0, stream>>>(pay, bcur, offs, ssrc);

    int nch = (RNUM + r_per - 1) / r_per;
    int aggGrid = NNODE / 4;

    for (int layer = 0; layer < 2; layer++) {
        const unsigned short* frag = layer ? frag2 : frag1;
        const unsigned short* rootf = (layer ? frag2 : frag1) + (size_t)RNUM * 4096;
        const float* bias = layer ? bias2 : bias1;
        for (int c = 0; c < nch; c++) {
            int r0 = c * r_per;
            int rcnt = (RNUM - r0 < r_per) ? (RNUM - r0) : r_per;
            int grid = (c == 0) ? (rcnt + 1) * NTB : rcnt * NTB;
            gemm_k<<<grid, 256, 0, stream>>>(xb, frag + (size_t)r0 * 4096, rootf,
                                             H, xrootb, rcnt);
            int flags = (c == 0 ? 1 : 0) | (c == nch - 1 ? 2 : 0) | (layer == 0 ? 4 : 0);
            if (rcnt == RNUM)
                agg_k<RNUM><<<aggGrid, 256, 0, stream>>>(H, offs, ssrc, xrootb, bias,
                                                         aggbuf, xb, out, 0, 0, rcnt, flags);
            else
                agg_k<0><<<aggGrid, 256, 0, stream>>>(H, offs, ssrc, xrootb, bias,
                                                      aggbuf, xb, out, r0, r0 * NNODE, rcnt, flags);
        }
    }
}